// Round 1
// 2906.167 us; speedup vs baseline: 1.1565x; 1.1565x over previous
//
#include <hip/hip_runtime.h>

// GRU bidirectional, B=4096 T=16 I=1024 H=1024, fp32 in/out, bf16 MFMA compute.
//
// Structure:
//   U[b*T+t, 0:3H]   = x[b,t,:] @ [W_izr; W_it]^T        (one big GEMM, bf16 out)
//   per step s (fwd processes x[s], bwd processes x[T-1-s], stacked M=2B):
//     Gh[m, 0:3H]    = h[m,:] @ [W_hzr; W_ht]^T           (GEMM, fp32 out)
//     gate kernel: r=sig(Ur+Ghr+b), z=sig(Uz+Ghz+b),
//                  h~=tanh(Ut+b_it + r*(Ght+b_ht)), h'=z*h~+(1-z)*h
//
// GEMM: 256x256 tile, BK=64, 8 waves (2Mx4N, each owns 128x64), 128 KiB LDS
// (2 dbuf x (A 32K + B 32K)), 8-phase schedule (2 K-tiles per outer iter):
//   per K-tile: 4 quadrant phases (mh,nh) in order (0,0)(0,1)(1,0)(1,1);
//   each phase: ds_read fragment subtile + stage ONE 16KB region of a future
//   K-tile -> s_barrier -> setprio(1) -> 16 MFMA -> setprio(0) -> s_barrier.
//   Region-gated in-place prefetch (issue only after the region's last
//   consuming phase's trailing barrier):
//     P1: A_U(t+1)->other buf   P2: A_L(t+2)->this buf (freed at P1)
//     P3: B_L(t+2)->this buf (freed at P1; B regs persist to P3)
//     P4: B_U(t+2)->this buf (freed at P2)
//   Single counted s_waitcnt vmcnt(6) per K-tile boundary: 3 regions
//   (=6 global_load_lds per wave) stay in flight across barriers.
// LDS bank-conflict fix: byte ^= ((row&7)<<4) applied BOTH on the global
// staging source (pre-swizzle) and on ds_read addresses (same involution);
// global_load_lds destinations stay linear (wave-uniform base + lane*16).
//
// Workspace layout (~668 MiB): x_bf bf16[B*T,I] | U bf16[B*T,3H] |
//   Wi bf16[3H,I] | Wh bf16[3H,H] | h_bf bf16[2B,H] | Gh f32[2B,3H] | h_f f32[2B,H]

#define BDIM 4096
#define TDIM 16
#define IDIM 1024
#define HDIM 1024

typedef __bf16 bf16;
typedef __attribute__((ext_vector_type(8))) __bf16 bf16x8;
typedef __attribute__((ext_vector_type(4))) __bf16 bf16x4;
typedef __attribute__((ext_vector_type(4))) float f32x4;

__device__ __forceinline__ void g2l16(const bf16* g, bf16* l) {
  __builtin_amdgcn_global_load_lds(
      (const __attribute__((address_space(1))) void*)g,
      (__attribute__((address_space(3))) void*)l, 16, 0, 0);
}

__device__ __forceinline__ float sigmoidf_(float x) {
  return 1.0f / (1.0f + __expf(-x));
}
__device__ __forceinline__ float tanhfast_(float x) {
  return 1.0f - 2.0f / (__expf(2.0f * x) + 1.0f);
}

// raw barrier (NO vmcnt drain) pinned against compiler code motion
#define GBAR()                          \
  do {                                  \
    __builtin_amdgcn_sched_barrier(0);  \
    __builtin_amdgcn_s_barrier();       \
    __builtin_amdgcn_sched_barrier(0);  \
  } while (0)

template <int MB, int NB>
__device__ __forceinline__ void mfma_block(f32x4 (&acc)[8][4],
                                           const bf16x8 (&a)[4][2],
                                           const bf16x8 (&b)[2][2]) {
#pragma unroll
  for (int mi = 0; mi < 4; ++mi)
#pragma unroll
    for (int j = 0; j < 2; ++j)
#pragma unroll
      for (int kk = 0; kk < 2; ++kk)
        acc[MB + mi][NB + j] = __builtin_amdgcn_mfma_f32_16x16x32_bf16(
            a[mi][kk], b[j][kk], acc[MB + mi][NB + j], 0, 0, 0);
}

// C[M,N] = A[M,K] @ B[N,K]^T, bf16 in, fp32 acc, CT out.
// Requires M%256==0, N%256==0, K%64==0, K>=192 (NT>=3), grid%8==0.
// Launch: 1-D grid of (M/256)*(N/256) blocks, 512 threads, 131072 B dyn LDS.
template <typename CT>
__global__ __launch_bounds__(512, 2)
void gemm256(const bf16* __restrict__ A, const bf16* __restrict__ B,
             CT* __restrict__ C, int N, int K, int nxb)
{
  extern __shared__ char lds[];
  // byte layout: [A buf0: 0) [A buf1: 32768) [B buf0: 65536) [B buf1: 98304)
  const int tid  = threadIdx.x;
  const int lane = tid & 63;
  const int wid  = tid >> 6;
  const int wm   = wid >> 2;   // 0..1  (wave rows: wm*128 .. +128)
  const int wn   = wid & 3;    // 0..3  (wave cols: wn*64 .. +64)

  // XCD-aware swizzle (grid % 8 == 0): each XCD gets a contiguous chunk.
  const int nwg = (int)gridDim.x;
  const int lin = ((int)blockIdx.x & 7) * (nwg >> 3) + ((int)blockIdx.x >> 3);
  const long bm = (long)(lin / nxb) * 256;
  const long bn = (long)(lin % nxb) * 256;

  const bf16* Ab = A + bm * K;
  const bf16* Bb = B + bn * K;
  const int NT = K >> 6;

  // ---- staging descriptors: 2 chunks of 16B per thread per 16KB region ----
  // Regions (per K-tile):
  //  A_L: tile rows {0-63,128-191}   (wave-local lower rows, read only in P1)
  //  A_U: tile rows {64-127,192-255} (read in P3; regs persist to P4)
  //  B_L: tile rows {0-31,64-95,128-159,192-223} (wave-local cols 0-31, P1)
  //  B_U: += 32                                   (wave-local cols 32-63, P2)
  // Physical LDS chunk o is linear per wave; global source is pre-swizzled:
  //  row = row(o); colb = (o&127) ^ ((row&7)<<4).
  const int o0 = tid * 16, o1 = o0 + 8192;
  const bf16 *gAL0, *gAL1, *gAU0, *gAU1, *gBL0, *gBL1, *gBU0, *gBU1;
  int dAL0, dAL1, dAU0, dAU1, dBL0, dBL1, dBU0, dBU1;
  {
    auto mkA = [&](int o, int up, const bf16*& g, int& d) {
      int r  = up * 64 + ((o >> 13) & 1) * 128 + ((o >> 7) & 63);
      int cb = (o & 127) ^ ((r & 7) << 4);
      g = Ab + (long)r * K + (cb >> 1);
      d = r * 128 + (o & 127);          // linear dest (== o + piece offset)
    };
    auto mkB = [&](int o, int up, const bf16*& g, int& d) {
      int r  = up * 32 + ((o >> 12) & 3) * 64 + ((o >> 7) & 31);
      int cb = (o & 127) ^ ((r & 7) << 4);
      g = Bb + (long)r * K + (cb >> 1);
      d = 65536 + r * 128 + (o & 127);
    };
    mkA(o0, 0, gAL0, dAL0); mkA(o1, 0, gAL1, dAL1);
    mkA(o0, 1, gAU0, dAU0); mkA(o1, 1, gAU1, dAU1);
    mkB(o0, 0, gBL0, dBL0); mkB(o1, 0, gBL1, dBL1);
    mkB(o0, 1, gBU0, dBU0); mkB(o1, 1, gBU1, dBU1);
  }
  auto STG = [&](const bf16* g, int d, int kt, int bo) {
    g2l16(g + (kt << 6), (bf16*)(lds + bo + d));
  };

  // ---- fragment read bases (swizzled). row&7 == fm&7 for all fragments,
  // so the XOR key is per-thread constant; kk=1 toggles bit 6 INSIDE the XOR.
  const int fm  = lane & 15;
  const int fkb = (lane >> 4) * 16;          // fk*2 bytes
  const int key = (fm & 7) << 4;
  const char* aB0 = lds + wm * 16384 + fm * 128 + (fkb ^ key);
  const char* aB1 = lds + wm * 16384 + fm * 128 + ((64 + fkb) ^ key);
  const char* bB0 = lds + 65536 + wn * 8192 + fm * 128 + (fkb ^ key);
  const char* bB1 = lds + 65536 + wn * 8192 + fm * 128 + ((64 + fkb) ^ key);

  // ---- prologue: K-tile 0 fully + K-tile 1 minus A_U (A_U(1) issues at t0.P1)
  STG(gAL0, dAL0, 0, 0);     STG(gAL1, dAL1, 0, 0);
  STG(gAU0, dAU0, 0, 0);     STG(gAU1, dAU1, 0, 0);
  STG(gBL0, dBL0, 0, 0);     STG(gBL1, dBL1, 0, 0);
  STG(gBU0, dBU0, 0, 0);     STG(gBU1, dBU1, 0, 0);
  STG(gAL0, dAL0, 1, 32768); STG(gAL1, dAL1, 1, 32768);
  STG(gBL0, dBL0, 1, 32768); STG(gBL1, dBL1, 1, 32768);
  STG(gBU0, dBU0, 1, 32768); STG(gBU1, dBU1, 1, 32768);
  asm volatile("s_waitcnt vmcnt(6)" ::: "memory");  // Ktile0 landed, 3 in flight
  GBAR();

  f32x4 acc[8][4] = {};
  bf16x8 aF[4][2], bLo[2][2], bHi[2][2];

  auto ktile = [&](int t, int CB, int NB) {
    // ---- P1 (mh0,nh0): read A-low + B-low; stage A_U(t+1) -> NB ----
#pragma unroll
    for (int mi = 0; mi < 4; ++mi)
#pragma unroll
      for (int kk = 0; kk < 2; ++kk)
        aF[mi][kk] = *(const bf16x8*)((kk ? aB1 : aB0) + CB + mi * 2048);
#pragma unroll
    for (int j = 0; j < 2; ++j)
#pragma unroll
      for (int kk = 0; kk < 2; ++kk)
        bLo[j][kk] = *(const bf16x8*)((kk ? bB1 : bB0) + CB + j * 2048);
    if (t + 1 < NT) { STG(gAU0, dAU0, t + 1, NB); STG(gAU1, dAU1, t + 1, NB); }
    GBAR();
    __builtin_amdgcn_s_setprio(1);
    mfma_block<0, 0>(acc, aF, bLo);
    __builtin_amdgcn_s_setprio(0);
    GBAR();
    // ---- P2 (mh0,nh1): read B-high; stage A_L(t+2) -> CB (freed at P1) ----
#pragma unroll
    for (int j = 0; j < 2; ++j)
#pragma unroll
      for (int kk = 0; kk < 2; ++kk)
        bHi[j][kk] = *(const bf16x8*)((kk ? bB1 : bB0) + CB + (2 + j) * 2048);
    if (t + 2 < NT) { STG(gAL0, dAL0, t + 2, CB); STG(gAL1, dAL1, t + 2, CB); }
    GBAR();
    __builtin_amdgcn_s_setprio(1);
    mfma_block<0, 2>(acc, aF, bHi);
    __builtin_amdgcn_s_setprio(0);
    GBAR();
    // ---- P3 (mh1,nh0): read A-high; stage B_L(t+2) -> CB (freed at P1) ----
#pragma unroll
    for (int mi = 0; mi < 4; ++mi)
#pragma unroll
      for (int kk = 0; kk < 2; ++kk)
        aF[mi][kk] = *(const bf16x8*)((kk ? aB1 : aB0) + CB + 8192 + mi * 2048);
    if (t + 2 < NT) { STG(gBL0, dBL0, t + 2, CB); STG(gBL1, dBL1, t + 2, CB); }
    GBAR();
    __builtin_amdgcn_s_setprio(1);
    mfma_block<4, 0>(acc, aF, bLo);     // bLo regs persist from P1
    __builtin_amdgcn_s_setprio(0);
    GBAR();
    // ---- P4 (mh1,nh1): stage B_U(t+2) -> CB (freed at P2); boundary wait ----
    if (t + 2 < NT) { STG(gBU0, dBU0, t + 2, CB); STG(gBU1, dBU1, t + 2, CB); }
    GBAR();
    __builtin_amdgcn_s_setprio(1);
    mfma_block<4, 2>(acc, aF, bHi);
    __builtin_amdgcn_s_setprio(0);
    // counted vmcnt: all of K-tile t+1 landed; A_L/B_L/B_U(t+2) stay in flight
    if (t + 2 < NT) { asm volatile("s_waitcnt vmcnt(6)" ::: "memory"); }
    else            { asm volatile("s_waitcnt vmcnt(0)" ::: "memory"); }
    GBAR();
  };

  for (int t = 0; t < NT; t += 2) {   // NT even (K=1024 -> 16)
    ktile(t,     0,     32768);
    ktile(t + 1, 32768, 0);
  }

  // ---- epilogue: C/D layout col=lane&15, row=(lane>>4)*4+reg ----
  const int rg = (lane >> 4) * 4;
  const int cg = lane & 15;
#pragma unroll
  for (int mi = 0; mi < 8; ++mi) {
#pragma unroll
    for (int j = 0; j < 4; ++j) {
      const long row0 = bm + wm * 128 + mi * 16 + rg;
      const long col  = bn + wn * 64 + j * 16 + cg;
#pragma unroll
      for (int r = 0; r < 4; ++r)
        C[(row0 + r) * (long)N + col] = (CT)acc[mi][j][r];
    }
  }
}

__global__ __launch_bounds__(256)
void conv_bf16(const float* __restrict__ src, bf16* __restrict__ dst, long n4) {
  long i = (long)blockIdx.x * blockDim.x + threadIdx.x;
  if (i >= n4) return;
  f32x4 v = *(const f32x4*)(src + i * 4);
  bf16x4 o;
  o[0] = (bf16)v[0]; o[1] = (bf16)v[1]; o[2] = (bf16)v[2]; o[3] = (bf16)v[3];
  *(bf16x4*)(dst + i * 4) = o;
}

__global__ __launch_bounds__(256)
void init_h(const float* __restrict__ h0, const float* __restrict__ bih0,
            float* __restrict__ hf, bf16* __restrict__ hb) {
  const long i4 = ((long)blockIdx.x * blockDim.x + threadIdx.x) * 4;
  const long nh = (long)BDIM * HDIM;
  const float* s = (i4 < nh) ? (h0 + i4) : (bih0 + (i4 - nh));
  f32x4 v = *(const f32x4*)s;
  *(f32x4*)(hf + i4) = v;
  bf16x4 o;
  o[0] = (bf16)v[0]; o[1] = (bf16)v[1]; o[2] = (bf16)v[2]; o[3] = (bf16)v[3];
  *(bf16x4*)(hb + i4) = o;
}

// grid = 2B blocks (one per (dir,b) row), 256 threads, 4 cols each.
__global__ __launch_bounds__(256)
void gate_step(const bf16* __restrict__ U, const float* __restrict__ Gh,
               float* __restrict__ hf, bf16* __restrict__ hb,
               const float* __restrict__ b_izr, const float* __restrict__ b_hzr,
               const float* __restrict__ b_it,  const float* __restrict__ b_ht,
               float* __restrict__ out, int s)
{
  const int m = blockIdx.x;             // 0..2B-1 (fwd rows then bwd rows)
  const int j = threadIdx.x * 4;        // 0..H-1
  const bool fwd = (m < BDIM);
  const int b  = fwd ? m : m - BDIM;
  const int tx = fwd ? s : (TDIM - 1 - s);   // x time index consumed this step
  const long urow = ((long)b * TDIM + tx) * (3 * HDIM);
  const long grow = (long)m * (3 * HDIM);
  const long hrow = (long)m * HDIM;

  bf16x4 ur = *(const bf16x4*)(U + urow + j);
  bf16x4 uz = *(const bf16x4*)(U + urow + HDIM + j);
  bf16x4 ut = *(const bf16x4*)(U + urow + 2 * HDIM + j);
  f32x4 gr = *(const f32x4*)(Gh + grow + j);
  f32x4 gz = *(const f32x4*)(Gh + grow + HDIM + j);
  f32x4 gt = *(const f32x4*)(Gh + grow + 2 * HDIM + j);
  f32x4 bri = *(const f32x4*)(b_izr + j);
  f32x4 bzi = *(const f32x4*)(b_izr + HDIM + j);
  f32x4 brh = *(const f32x4*)(b_hzr + j);
  f32x4 bzh = *(const f32x4*)(b_hzr + HDIM + j);
  f32x4 bti = *(const f32x4*)(b_it + j);
  f32x4 bth = *(const f32x4*)(b_ht + j);
  f32x4 hp = *(const f32x4*)(hf + hrow + j);

  f32x4 hn;
  bf16x4 hnb;
#pragma unroll
  for (int c = 0; c < 4; ++c) {
    float r = sigmoidf_((float)ur[c] + gr[c] + bri[c] + brh[c]);
    float z = sigmoidf_((float)uz[c] + gz[c] + bzi[c] + bzh[c]);
    float ht = tanhfast_((float)ut[c] + bti[c] + r * (gt[c] + bth[c]));
    float v = z * ht + (1.0f - z) * hp[c];
    hn[c] = v;
    hnb[c] = (bf16)v;
  }
  *(f32x4*)(hf + hrow + j) = hn;
  *(bf16x4*)(hb + hrow + j) = hnb;

  float* op = fwd
      ? (out + ((long)b * TDIM + (TDIM - 1 - s)) * (2 * HDIM) + j)
      : (out + ((long)b * TDIM + s) * (2 * HDIM) + HDIM + j);
  *(f32x4*)op = hn;
}

extern "C" void kernel_launch(void* const* d_in, const int* in_sizes, int n_in,
                              void* d_out, int out_size, void* d_ws, size_t ws_size,
                              hipStream_t stream) {
  const float* x     = (const float*)d_in[0];   // [B,T,I]
  const float* h0    = (const float*)d_in[1];   // [B,H]
  const float* bih0  = (const float*)d_in[2];   // [B,H]
  const float* W_izr = (const float*)d_in[3];   // [2H,I]
  const float* b_izr = (const float*)d_in[4];   // [2H]
  const float* W_hzr = (const float*)d_in[5];   // [2H,H]
  const float* b_hzr = (const float*)d_in[6];   // [2H]
  const float* W_it  = (const float*)d_in[7];   // [H,I]
  const float* b_it  = (const float*)d_in[8];   // [H]
  const float* W_ht  = (const float*)d_in[9];   // [H,H]
  const float* b_ht  = (const float*)d_in[10];  // [H]
  float* out = (float*)d_out;                   // [B,T,2H]

  const long n_x  = (long)BDIM * TDIM * IDIM;       // 67,108,864
  const long n_U  = (long)BDIM * TDIM * 3 * HDIM;   // 201,326,592
  const long n_Wi = (long)3 * HDIM * IDIM;          // 3,145,728
  const long n_Wh = (long)3 * HDIM * HDIM;          // 3,145,728
  const long n_h  = (long)2 * BDIM * HDIM;          // 8,388,608
  const long n_Gh = (long)2 * BDIM * 3 * HDIM;      // 25,165,824

  bf16* x_bf = (bf16*)d_ws;
  bf16* U    = x_bf + n_x;
  bf16* Wi   = U + n_U;
  bf16* Wh   = Wi + n_Wi;
  bf16* h_bf = Wh + n_Wh;
  float* Gh  = (float*)(h_bf + n_h);
  float* h_f = Gh + n_Gh;

  // 128 KiB dynamic LDS opt-in (host-side attribute set; not a stream op,
  // safe under graph capture; idempotent).
  (void)hipFuncSetAttribute((const void*)gemm256<bf16>,
                            hipFuncAttributeMaxDynamicSharedMemorySize, 131072);
  (void)hipFuncSetAttribute((const void*)gemm256<float>,
                            hipFuncAttributeMaxDynamicSharedMemorySize, 131072);

  // --- phase 0: conversions ---
  conv_bf16<<<(unsigned)(n_x / 4 / 256), 256, 0, stream>>>(x, x_bf, n_x / 4);
  conv_bf16<<<(unsigned)(2 * HDIM * IDIM / 4 / 256), 256, 0, stream>>>(
      W_izr, Wi, 2L * HDIM * IDIM / 4);
  conv_bf16<<<(unsigned)(HDIM * IDIM / 4 / 256), 256, 0, stream>>>(
      W_it, Wi + 2L * HDIM * IDIM, (long)HDIM * IDIM / 4);
  conv_bf16<<<(unsigned)(2 * HDIM * HDIM / 4 / 256), 256, 0, stream>>>(
      W_hzr, Wh, 2L * HDIM * HDIM / 4);
  conv_bf16<<<(unsigned)(HDIM * HDIM / 4 / 256), 256, 0, stream>>>(
      W_ht, Wh + 2L * HDIM * HDIM, (long)HDIM * HDIM / 4);
  init_h<<<(unsigned)(n_h / 4 / 256), 256, 0, stream>>>(h0, bih0, h_f, h_bf);

  // --- phase 1: U = X @ Wi^T  (M=65536, N=3072, K=1024): 3072 blocks ---
  gemm256<bf16><<<dim3((BDIM * TDIM / 256) * (3 * HDIM / 256)), dim3(512),
                  131072, stream>>>(x_bf, Wi, U, 3 * HDIM, IDIM, 3 * HDIM / 256);

  // --- phase 2: 16 recurrent steps, fwd+bwd stacked (M=8192): 384 blocks ---
  for (int s = 0; s < TDIM; ++s) {
    gemm256<float><<<dim3((2 * BDIM / 256) * (3 * HDIM / 256)), dim3(512),
                     131072, stream>>>(h_bf, Wh, Gh, 3 * HDIM, HDIM,
                                       3 * HDIM / 256);
    gate_step<<<2 * BDIM, 256, 0, stream>>>(U, Gh, h_f, h_bf,
                                            b_izr, b_hzr, b_it, b_ht, out, s);
  }
}